// Round 14
// baseline (26.569 us; speedup 1.0000x reference)
//
#include <hip/hip_runtime.h>
#include <math.h>

#define EPS 1e-8f

typedef _Float16 h8 __attribute__((ext_vector_type(8)));
typedef float f32x16 __attribute__((ext_vector_type(16)));

// sin/cos of -2*pi*ph/200 via v_sin_f32/v_cos_f32 (input in revolutions, |x|<1)
static __device__ __forceinline__ void fsincos(int ph, float* s, float* c) {
    float x = (float)ph * (-1.0f / 200.0f);
    *s = __builtin_amdgcn_sinf(x);
    *c = __builtin_amdgcn_cosf(x);
}

// ws layout (float offsets)
#define WS_WMAX 0        // 50
#define WS_WN   64       // 800
#define WS_RCPA 1024     // 5200: reciprocal of |fft_sig| window
#define WS_A2   8192     // f16 frags [4 tm][4 pks][64 l][8 s] = 8192 f16 (hi only)
#define WS_B3   16384    // f16 frags [4 tn][16 pks][64 l][8 s] = 32768 f16 (hi+lo, interleaved cols)

// Shared A/B fragment k-map (identical for builders & consumers):
//   row/col = 32*tile + (l&31);  k = 16*ks + 8*(l>>5) + s

// ---- prologue: amp (blocks 0..162) + tables/fragments (163..194) -----------
__global__ __launch_bounds__(256) void k_prelude(const float* __restrict__ w,
                                                 const float* __restrict__ fs,
                                                 float* __restrict__ ws) {
    const int blk = blockIdx.x, t = threadIdx.x;
    if (blk < 163) {
        __shared__ float tc[200], tsn[200];
        for (int i = t; i < 200; i += 256) {
            float s, c;
            fsincos(i, &s, &c);
            tc[i] = c; tsn[i] = s;
        }
        __syncthreads();
        int gid = blk * 256 + t;
        int q = gid >> 3, part = gid & 7;
        float aR = 0.f, aI = 0.f;
        if (q < 5200) {
            int s_ = q / 52, u = q - s_ * 52;
            int k = (150 + s_) % 200;
            int j = 101 + u;
            int ph = (k * (part * 25)) % 200;
            for (int r = part * 25; r < part * 25 + 25; ++r) {
                float v = fs[r * 200 + j];
                aR = fmaf(v, tc[ph], aR);
                aI = fmaf(v, tsn[ph], aI);
                ph += k; if (ph >= 200) ph -= 200;
            }
        }
        aR += __shfl_xor(aR, 1); aI += __shfl_xor(aI, 1);
        aR += __shfl_xor(aR, 2); aI += __shfl_xor(aI, 2);
        aR += __shfl_xor(aR, 4); aI += __shfl_xor(aI, 4);
        if (q < 5200 && part == 0)
            ws[WS_RCPA + q] = 1.0f / sqrtf(aR * aR + aI * aI);
    } else {
        int gid = (blk - 163) * 256 + t;   // 0..8191
        if (gid < 50) {
            float mx = 0.f, vals[16];
            for (int q = 0; q < 16; ++q) {
                float v = fabsf(w[gid * 16 + q]);
                vals[q] = v; mx = fmaxf(mx, v);
            }
            ws[WS_WMAX + gid] = mx;
            float d = mx + EPS;
            for (int q = 0; q < 16; ++q) ws[WS_WN + gid * 16 + q] = vals[q] / d;
        }
        // A2 (hi only) = [cR(50); cI(50); 0] rows x k(0..48)
        {
            _Float16* A2h = (_Float16*)(ws + WS_A2);
            int a = gid;   // exactly 8192 threads
            int s = a & 7, l = (a >> 3) & 63, pks = (a >> 9) & 3, tm = a >> 11;
            int row = 32 * tm + (l & 31);
            int k = 16 * pks + 8 * (l >> 5) + s;
            float X = 0.f;
            if (row < 100 && k < 49) {
                int m = (row < 50) ? row : row - 50;
                int kk = (175 + m) % 200;
                int ph = (kk * (75 + k)) % 200;
                float sn, cs;
                fsincos(ph, &sn, &cs);
                X = (row < 50) ? cs : sn;
            }
            A2h[a] = (_Float16)X;
        }
        // B3 INTERLEAVED: col n' = 2*cc + isI (0..103)
        //   isI=0: kap<64 ? eR : -eI ;  isI=1: kap<64 ? eI : eR
        _Float16* B3h = (_Float16*)(ws + WS_B3);
        for (int bI = gid; bI < 32768; bI += 8192) {
            int s = bI & 7, l = (bI >> 3) & 63, pks = (bI >> 9) & 15, tn = bI >> 13;
            int part = pks >> 3;
            int np = 32 * tn + (l & 31);
            int kap = 16 * (pks & 7) + 8 * (l >> 5) + s;
            float X = 0.f;
            if (np < 104) {
                int cc = np >> 1;
                int j = kap & 63;
                int ph = ((cc + 1) * j) % 200;
                float sn, cs;
                fsincos(ph, &sn, &cs);
                X = (np & 1) ? ((kap < 64) ? sn : cs) : ((kap < 64) ? cs : -sn);
            }
            _Float16 hi = (_Float16)X;
            B3h[bI] = part ? (_Float16)(X - (float)hi) : hi;
        }
    }
}

// -------- main batched kernel: one block (512 thr = 8 waves) per batch ------
__global__ __launch_bounds__(512, 4) void k_main(const float* __restrict__ in,
                                                 const float* __restrict__ bias,
                                                 const float* __restrict__ fs,
                                                 const float* __restrict__ ws,
                                                 float* __restrict__ out) {
    __shared__ __align__(16) char R1[16384];   // B2 frags; later absG f32[2600]
    __shared__ __align__(16) char R2[16640];   // A3 hi frags [2 tm3][8 pks][65 slots][8 s] f16
    __shared__ float xpat[50][16];
    __shared__ float imax_s[50];
    __shared__ float inv_s[50];
    __shared__ float res_s[26][50];
    __shared__ __align__(16) float red8[8];

    const int t = threadIdx.x;
    const int b = blockIdx.x;
    const int lane = t & 63;
    const int wid = t >> 6;                               // 0..7
    const int swid = __builtin_amdgcn_readfirstlane(wid);
    const float* ib = in + b * 784;

    // ph2 / ph3 tile coordinates for this wave
    const int tmP = swid >> 1, tnP = swid & 1;
    const int tm3 = swid >> 2, tn3 = swid & 3;
    const h8* wsA2 = (const h8*)(ws + WS_A2);
    const h8* wsB3 = (const h8*)(ws + WS_B3);

    // TOP prefetch 1: fs values for this thread's B2 fragment
    const int p1_l = t & 63;
    const int p1_ksq = (t >> 6) & 3;
    const int p1_tn = t >> 8;                 // 0..1
    const int p1_j = (p1_l & 31) + 32 * p1_tn;
    const int p1_i0 = 16 * p1_ksq + 8 * (p1_l >> 5);
    float fsv[8];
    #pragma unroll
    for (int s = 0; s < 8; ++s) {
        int i = p1_i0 + s;
        fsv[s] = (i < 49) ? fs[(75 + i) * 200 + p1_j] : 0.f;
    }
    // TOP prefetch 2: A2 fragments (batch-independent; in flight across P0/P1)
    h8 a2f[4];
    #pragma unroll
    for (int kq = 0; kq < 4; ++kq) a2f[kq] = wsA2[(tmP * 4 + kq) * 64 + lane];

    // P0: patches (float4) + per-row max via quad shuffle
    if (t < 196) {
        int row = t >> 2, s4 = t & 3;
        int pr = row / 7, pc = row - pr * 7;
        float4 v4 = *(const float4*)(ib + (pr * 4 + s4) * 28 + pc * 4);
        *(float4*)(&xpat[row][s4 * 4]) = v4;
        float mx = fmaxf(fmaxf(v4.x, v4.y), fmaxf(v4.z, v4.w));
        mx = fmaxf(mx, __shfl_xor(mx, 1));
        mx = fmaxf(mx, __shfl_xor(mx, 2));
        if (s4 == 0) { imax_s[row] = mx; inv_s[row] = 1.f / (mx + EPS); }
    }
    // zero R2 (stale-LDS insurance for unwritten m>=50 slots)
    {
        h8 z;
        #pragma unroll
        for (int s = 0; s < 8; ++s) z[s] = (_Float16)0.f;
        for (int o = t; o < 1040; o += 512) *(h8*)(R2 + (o << 4)) = z;
    }
    __syncthreads();

    // P1: B2 frags from prefetched fs; two ds_write_b128 per thread
    {
        h8 hiv, lov;
        #pragma unroll
        for (int s = 0; s < 8; ++s) {
            int i = p1_i0 + s;
            float v = 0.f;
            if (i < 49) v = fsv[s] * xpat[i][p1_j >> 2] * inv_s[i];
            _Float16 hi = (_Float16)v;
            hiv[s] = hi;
            lov[s] = (_Float16)(v - (float)hi);
        }
        _Float16* B2h = (_Float16*)R1;
        const int base0 = ((p1_tn * 8 + p1_ksq) * 64 + p1_l) * 8;
        *(h8*)(B2h + base0) = hiv;
        *(h8*)(B2h + base0 + 2048) = lov;
    }
    __syncthreads();

    // P2: issue B3-hi + wn prefetch, then ph2 MFMA with A2 already in regs;
    // issue B3-lo after the chain; epilogue scatters into padded A3 layout.
    h8 b3h[8], b3l[8];
    {
        #pragma unroll
        for (int k = 0; k < 8; ++k) b3h[k] = wsB3[(tn3 * 16 + k) * 64 + lane];
        const float* wn = ws + WS_WN;
        const int j = (lane & 31) + 32 * tnP;
        const int q = j >> 2;
        float wnv[16];
        #pragma unroll
        for (int r = 0; r < 16; ++r) {
            int row = (r & 3) + 8 * (r >> 2) + 4 * (lane >> 5) + 32 * tmP;
            int m = (row < 50) ? row : (row < 100 ? row - 50 : 0);
            wnv[r] = wn[m * 16 + q];
        }

        f32x16 acc0, acc1;
        #pragma unroll
        for (int i = 0; i < 16; ++i) { acc0[i] = 0.f; acc1[i] = 0.f; }
        #pragma unroll
        for (int kq = 0; kq < 4; ++kq) {
            h8 bhi = *(const h8*)(R1 + (((tnP * 8 + kq) * 64 + lane) << 4));
            h8 blo = *(const h8*)(R1 + (((tnP * 8 + kq + 4) * 64 + lane) << 4));
            acc0 = __builtin_amdgcn_mfma_f32_32x32x16_f16(a2f[kq], bhi, acc0, 0, 0, 0);
            acc1 = __builtin_amdgcn_mfma_f32_32x32x16_f16(a2f[kq], blo, acc1, 0, 0, 0);
        }
        // B3-lo in flight during scatter + barrier drain
        #pragma unroll
        for (int k = 0; k < 8; ++k) b3l[k] = wsB3[(tn3 * 16 + 8 + k) * 64 + lane];

        f32x16 acc = acc0 + acc1;
        _Float16* A3h = (_Float16*)R2;
        #pragma unroll
        for (int r = 0; r < 16; ++r) {
            int row = (r & 3) + 8 * (r >> 2) + 4 * (lane >> 5) + 32 * tmP;
            if (row < 100) {
                int m = (row < 50) ? row : row - 50;
                float v = acc[r] * wnv[r];
                int kap = j + ((row < 50) ? 0 : 64);
                int tmw = m >> 5;
                int pks = kap >> 4;                    // 0..7
                int bb = (kap >> 3) & 1;
                int elem = ((tmw * 8 + pks) * 65 + (m & 31) + 33 * bb) * 8 + (kap & 7);
                A3h[elem] = (_Float16)v;
            }
        }
    }
    __syncthreads();

    // P3: ph3 MFMA with B3 fully in registers; hi chain then lo chain;
    // epilogue fuses |G| via adjacent-lane shfl -> absG (overlays R1)
    {
        f32x16 acc0, acc1;
        #pragma unroll
        for (int i = 0; i < 16; ++i) { acc0[i] = 0.f; acc1[i] = 0.f; }
        const int aoff = lane + (lane >> 5);           // padded read index
        #pragma unroll
        for (int kq = 0; kq < 8; ++kq) {
            h8 a = *(const h8*)(R2 + (((tm3 * 8 + kq) * 65 + aoff) << 4));
            acc0 = __builtin_amdgcn_mfma_f32_32x32x16_f16(a, b3h[kq], acc0, 0, 0, 0);
        }
        #pragma unroll
        for (int kq = 0; kq < 8; ++kq) {
            h8 a = *(const h8*)(R2 + (((tm3 * 8 + kq) * 65 + aoff) << 4));
            acc1 = __builtin_amdgcn_mfma_f32_32x32x16_f16(a, b3l[kq], acc1, 0, 0, 0);
        }
        f32x16 acc = acc0 + acc1;
        const int np = (lane & 31) + 32 * tn3;
        float* aG = (float*)R1;
        if (np < 104) {
            const int cc = np >> 1;
            const bool wr = !(np & 1);
            #pragma unroll
            for (int r = 0; r < 16; ++r) {
                int row = (r & 3) + 8 * (r >> 2) + 4 * (lane >> 5) + 32 * tm3;
                float g = acc[r];
                float gp = __shfl_xor(g, 1);
                if (row < 50 && wr) aG[row * 52 + cc] = sqrtf(g * g + gp * gp);
            }
        }
    }
    __syncthreads();

    // P4: pool absG (2x3/2x1); r = v * min(rcp-amp window)
    const float* ra = ws + WS_RCPA;
    const float* aG = (const float*)R1;
    float local = 0.f;
    for (int o = t; o < 1300; o += 512) {
        int hh = o / 50, w2 = o - hh * 50;
        int h = hh + 12;
        int m1 = 2 * h - 25, m2 = m1 + 1;
        float v = 0.f;
        #pragma unroll
        for (int du = 0; du < 3; ++du) {
            int u = w2 + du;
            if (m1 >= 0) v = fmaxf(v, aG[m1 * 52 + u]);
            if (m2 < 50) v = fmaxf(v, aG[m2 * 52 + u]);
        }
        float rc = ra[(2 * h) * 52 + w2];
        #pragma unroll
        for (int du = 1; du < 3; ++du) rc = fminf(rc, ra[(2 * h) * 52 + w2 + du]);
        #pragma unroll
        for (int du = 0; du < 3; ++du) rc = fminf(rc, ra[(2 * h + 1) * 52 + w2 + du]);
        float r = v * rc;
        res_s[hh][w2] = r;
        local = fmaxf(local, r);
    }
    #pragma unroll
    for (int off = 32; off > 0; off >>= 1)
        local = fmaxf(local, __shfl_xor(local, off));
    if (lane == 0) red8[wid] = local;
    __syncthreads();

    float mres;
    {
        float4 r0 = *(const float4*)&red8[0];
        float4 r1 = *(const float4*)&red8[4];
        float m0 = fmaxf(fmaxf(r0.x, r0.y), fmaxf(r0.z, r0.w));
        float m1 = fmaxf(fmaxf(r1.x, r1.y), fmaxf(r1.z, r1.w));
        mres = fmaxf(m0, m1);
    }
    float invm = 1.f / (mres + EPS);

    // P5: out[b,r,c] = bias[r,c] + res[c,r]*invm * imax[r]*wmax[c]
    const float* wmaxg = ws + WS_WMAX;
    for (int o = t; o < 2450; o += 512) {
        int r = o / 50, c = o - r * 50;
        float val = bias[o];
        if (c >= 12 && c < 38)
            val = fmaf(res_s[c - 12][r] * invm, imax_s[r] * wmaxg[c], val);
        out[b * 2450 + o] = val;
    }
}

extern "C" void kernel_launch(void* const* d_in, const int* in_sizes, int n_in,
                              void* d_out, int out_size, void* d_ws, size_t ws_size,
                              hipStream_t stream) {
    const float* in   = (const float*)d_in[0];   // [512,1,28,28]
    const float* w    = (const float*)d_in[1];   // [50,16]
    const float* bias = (const float*)d_in[2];   // [1,49,50]
    const float* fs   = (const float*)d_in[3];   // [200,200]
    float* out = (float*)d_out;                  // [512,49,50] f32
    float* ws  = (float*)d_ws;

    hipLaunchKernelGGL(k_prelude, dim3(195),  dim3(256), 0, stream, w, fs, ws);
    hipLaunchKernelGGL(k_main,    dim3(512),  dim3(512), 0, stream, in, bias, fs, ws, out);
}

// Round 16
// 23.984 us; speedup vs baseline: 1.1078x; 1.1078x over previous
//
#include <hip/hip_runtime.h>
#include <math.h>

#define EPS 1e-8f

typedef _Float16 h8 __attribute__((ext_vector_type(8)));
typedef float f32x16 __attribute__((ext_vector_type(16)));

// sin/cos of -2*pi*ph/200 via v_sin_f32/v_cos_f32 (input in revolutions, |x|<1)
static __device__ __forceinline__ void fsincos(int ph, float* s, float* c) {
    float x = (float)ph * (-1.0f / 200.0f);
    *s = __builtin_amdgcn_sinf(x);
    *c = __builtin_amdgcn_cosf(x);
}

// ws layout (float offsets)
#define WS_WMAX 0        // 50
#define WS_WN   64       // 800
#define WS_RCPA 1024     // 5200: reciprocal of |fft_sig| window
#define WS_A2   8192     // f16 frags [4 tm][4 pks][64 l][8 s] = 8192 f16 (hi only)
#define WS_B3   16384    // f16 frags [4 tn][16 pks][64 l][8 s] = 32768 f16 (hi+lo, interleaved cols)

// Shared A/B fragment k-map (identical for builders & consumers):
//   row/col = 32*tile + (l&31);  k = 16*ks + 8*(l>>5) + s

// ---- prologue: amp (blocks 0..162) + tables/fragments (163..194) -----------
__global__ __launch_bounds__(256) void k_prelude(const float* __restrict__ w,
                                                 const float* __restrict__ fs,
                                                 float* __restrict__ ws) {
    const int blk = blockIdx.x, t = threadIdx.x;
    if (blk < 163) {
        __shared__ float tc[200], tsn[200];
        for (int i = t; i < 200; i += 256) {
            float s, c;
            fsincos(i, &s, &c);
            tc[i] = c; tsn[i] = s;
        }
        __syncthreads();
        int gid = blk * 256 + t;
        int q = gid >> 3, part = gid & 7;
        float aR = 0.f, aI = 0.f;
        if (q < 5200) {
            int s_ = q / 52, u = q - s_ * 52;
            int k = (150 + s_) % 200;
            int j = 101 + u;
            int ph = (k * (part * 25)) % 200;
            for (int r = part * 25; r < part * 25 + 25; ++r) {
                float v = fs[r * 200 + j];
                aR = fmaf(v, tc[ph], aR);
                aI = fmaf(v, tsn[ph], aI);
                ph += k; if (ph >= 200) ph -= 200;
            }
        }
        aR += __shfl_xor(aR, 1); aI += __shfl_xor(aI, 1);
        aR += __shfl_xor(aR, 2); aI += __shfl_xor(aI, 2);
        aR += __shfl_xor(aR, 4); aI += __shfl_xor(aI, 4);
        if (q < 5200 && part == 0)
            ws[WS_RCPA + q] = 1.0f / sqrtf(aR * aR + aI * aI);
    } else {
        int gid = (blk - 163) * 256 + t;   // 0..8191
        if (gid < 50) {
            float mx = 0.f, vals[16];
            for (int q = 0; q < 16; ++q) {
                float v = fabsf(w[gid * 16 + q]);
                vals[q] = v; mx = fmaxf(mx, v);
            }
            ws[WS_WMAX + gid] = mx;
            float d = mx + EPS;
            for (int q = 0; q < 16; ++q) ws[WS_WN + gid * 16 + q] = vals[q] / d;
        }
        // A2 (hi only) = [cR(50); cI(50); 0] rows x k(0..48)
        {
            _Float16* A2h = (_Float16*)(ws + WS_A2);
            int a = gid;   // exactly 8192 threads
            int s = a & 7, l = (a >> 3) & 63, pks = (a >> 9) & 3, tm = a >> 11;
            int row = 32 * tm + (l & 31);
            int k = 16 * pks + 8 * (l >> 5) + s;
            float X = 0.f;
            if (row < 100 && k < 49) {
                int m = (row < 50) ? row : row - 50;
                int kk = (175 + m) % 200;
                int ph = (kk * (75 + k)) % 200;
                float sn, cs;
                fsincos(ph, &sn, &cs);
                X = (row < 50) ? cs : sn;
            }
            A2h[a] = (_Float16)X;
        }
        // B3 INTERLEAVED: col n' = 2*cc + isI (0..103)
        //   isI=0: kap<64 ? eR : -eI ;  isI=1: kap<64 ? eI : eR
        _Float16* B3h = (_Float16*)(ws + WS_B3);
        for (int bI = gid; bI < 32768; bI += 8192) {
            int s = bI & 7, l = (bI >> 3) & 63, pks = (bI >> 9) & 15, tn = bI >> 13;
            int part = pks >> 3;
            int np = 32 * tn + (l & 31);
            int kap = 16 * (pks & 7) + 8 * (l >> 5) + s;
            float X = 0.f;
            if (np < 104) {
                int cc = np >> 1;
                int j = kap & 63;
                int ph = ((cc + 1) * j) % 200;
                float sn, cs;
                fsincos(ph, &sn, &cs);
                X = (np & 1) ? ((kap < 64) ? sn : cs) : ((kap < 64) ? cs : -sn);
            }
            _Float16 hi = (_Float16)X;
            B3h[bI] = part ? (_Float16)(X - (float)hi) : hi;
        }
    }
}

// -------- main batched kernel: one block (512 thr = 8 waves) per batch ------
// __launch_bounds__(512, 6): 6 waves/SIMD -> 3 blocks/CU (LDS ~41KB x3 = 123KB)
__global__ __launch_bounds__(512, 6) void k_main(const float* __restrict__ in,
                                                 const float* __restrict__ bias,
                                                 const float* __restrict__ fs,
                                                 const float* __restrict__ ws,
                                                 float* __restrict__ out) {
    __shared__ __align__(16) char R1[16384];   // B2 hi frags (8KB); later absG f32[2600]
    __shared__ __align__(16) char R2[16640];   // A3 hi frags [2 tm3][8 pks][65 slots][8 s] f16
    __shared__ float xpat[50][16];
    __shared__ float imax_s[50];
    __shared__ float inv_s[50];
    __shared__ float res_s[26][50];
    __shared__ __align__(16) float red8[8];

    const int t = threadIdx.x;
    const int b = blockIdx.x;
    const int lane = t & 63;
    const int wid = t >> 6;                               // 0..7
    const int swid = __builtin_amdgcn_readfirstlane(wid);
    const float* ib = in + b * 784;

    // TOP prefetch: fs values for this thread's B2 fragment (indep of P0)
    const int p1_l = t & 63;
    const int p1_ksq = (t >> 6) & 3;
    const int p1_tn = t >> 8;                 // 0..1
    const int p1_j = (p1_l & 31) + 32 * p1_tn;
    const int p1_i0 = 16 * p1_ksq + 8 * (p1_l >> 5);
    float fsv[8];
    #pragma unroll
    for (int s = 0; s < 8; ++s) {
        int i = p1_i0 + s;
        fsv[s] = (i < 49) ? fs[(75 + i) * 200 + p1_j] : 0.f;
    }

    // P0: patches (float4) + per-row max via quad shuffle
    if (t < 196) {
        int row = t >> 2, s4 = t & 3;
        int pr = row / 7, pc = row - pr * 7;
        float4 v4 = *(const float4*)(ib + (pr * 4 + s4) * 28 + pc * 4);
        *(float4*)(&xpat[row][s4 * 4]) = v4;
        float mx = fmaxf(fmaxf(v4.x, v4.y), fmaxf(v4.z, v4.w));
        mx = fmaxf(mx, __shfl_xor(mx, 1));
        mx = fmaxf(mx, __shfl_xor(mx, 2));
        if (s4 == 0) { imax_s[row] = mx; inv_s[row] = 1.f / (mx + EPS); }
    }
    // (no R2 zeroing: MFMA rows are independent; garbage A3 rows m>=50 only
    //  produce garbage G rows m>=50, which the epilogue discards)
    __syncthreads();

    // P1: B2 hi frags from prefetched fs; one ds_write_b128 per thread
    {
        h8 hiv;
        #pragma unroll
        for (int s = 0; s < 8; ++s) {
            int i = p1_i0 + s;
            float v = 0.f;
            if (i < 49) v = fsv[s] * xpat[i][p1_j >> 2] * inv_s[i];
            hiv[s] = (_Float16)v;
        }
        _Float16* B2h = (_Float16*)R1;
        *(h8*)(B2h + ((p1_tn * 4 + p1_ksq) * 64 + p1_l) * 8) = hiv;
    }
    __syncthreads();

    // P2: ph2 MFMA D[128][64] = c_hi @ T_hi, 4 K-steps, single chain;
    // epilogue scatters D*wn (hi f16) into padded A3 frag layout
    {
        const int tm = swid >> 1, tn = swid & 1;
        f32x16 acc;
        #pragma unroll
        for (int i = 0; i < 16; ++i) acc[i] = 0.f;
        const h8* wsA2 = (const h8*)(ws + WS_A2);
        #pragma unroll
        for (int kq = 0; kq < 4; ++kq) {
            h8 a   = wsA2[(tm * 4 + kq) * 64 + lane];
            h8 bhi = *(const h8*)(R1 + (((tn * 4 + kq) * 64 + lane) << 4));
            acc = __builtin_amdgcn_mfma_f32_32x32x16_f16(a, bhi, acc, 0, 0, 0);
        }
        const float* wn = ws + WS_WN;
        const int j = (lane & 31) + 32 * tn;
        const int q = j >> 2;
        _Float16* A3h = (_Float16*)R2;
        #pragma unroll
        for (int r = 0; r < 16; ++r) {
            int row = (r & 3) + 8 * (r >> 2) + 4 * (lane >> 5) + 32 * tm;
            if (row < 100) {
                int m = (row < 50) ? row : row - 50;
                float v = acc[r] * wn[m * 16 + q];
                int kap = j + ((row < 50) ? 0 : 64);
                int tmw = m >> 5;
                int pks = kap >> 4;                    // 0..7
                int bb = (kap >> 3) & 1;
                int elem = ((tmw * 8 + pks) * 65 + (m & 31) + 33 * bb) * 8 + (kap & 7);
                A3h[elem] = (_Float16)v;
            }
        }
    }
    __syncthreads();

    // P3: ph3 MFMA G'[64][128] = O_hi @ (B_hi + B_lo), 16 K-steps, dual acc;
    // epilogue fuses |G| via adjacent-lane shfl -> absG (overlays R1)
    {
        const int tm3 = swid >> 2, tn3 = swid & 3;
        f32x16 acc0, acc1;
        #pragma unroll
        for (int i = 0; i < 16; ++i) { acc0[i] = 0.f; acc1[i] = 0.f; }
        const h8* wsB3 = (const h8*)(ws + WS_B3);
        const int aoff = lane + (lane >> 5);           // padded read index
        #pragma unroll
        for (int kq = 0; kq < 8; ++kq) {
            h8 a   = *(const h8*)(R2 + (((tm3 * 8 + kq) * 65 + aoff) << 4));
            h8 bhi = wsB3[(tn3 * 16 + kq) * 64 + lane];
            h8 blo = wsB3[(tn3 * 16 + kq + 8) * 64 + lane];
            acc0 = __builtin_amdgcn_mfma_f32_32x32x16_f16(a, bhi, acc0, 0, 0, 0);
            acc1 = __builtin_amdgcn_mfma_f32_32x32x16_f16(a, blo, acc1, 0, 0, 0);
        }
        f32x16 acc = acc0 + acc1;
        const int np = (lane & 31) + 32 * tn3;
        float* aG = (float*)R1;
        if (np < 104) {
            const int cc = np >> 1;
            const bool wr = !(np & 1);
            #pragma unroll
            for (int r = 0; r < 16; ++r) {
                int row = (r & 3) + 8 * (r >> 2) + 4 * (lane >> 5) + 32 * tm3;
                float g = acc[r];
                float gp = __shfl_xor(g, 1);
                if (row < 50 && wr) aG[row * 52 + cc] = sqrtf(g * g + gp * gp);
            }
        }
    }
    __syncthreads();

    // P4: pool absG (2x3/2x1); r = v * min(rcp-amp window)
    const float* ra = ws + WS_RCPA;
    const float* aG = (const float*)R1;
    float local = 0.f;
    for (int o = t; o < 1300; o += 512) {
        int hh = o / 50, w2 = o - hh * 50;
        int h = hh + 12;
        int m1 = 2 * h - 25, m2 = m1 + 1;
        float v = 0.f;
        #pragma unroll
        for (int du = 0; du < 3; ++du) {
            int u = w2 + du;
            if (m1 >= 0) v = fmaxf(v, aG[m1 * 52 + u]);
            if (m2 < 50) v = fmaxf(v, aG[m2 * 52 + u]);
        }
        float rc = ra[(2 * h) * 52 + w2];
        #pragma unroll
        for (int du = 1; du < 3; ++du) rc = fminf(rc, ra[(2 * h) * 52 + w2 + du]);
        #pragma unroll
        for (int du = 0; du < 3; ++du) rc = fminf(rc, ra[(2 * h + 1) * 52 + w2 + du]);
        float r = v * rc;
        res_s[hh][w2] = r;
        local = fmaxf(local, r);
    }
    #pragma unroll
    for (int off = 32; off > 0; off >>= 1)
        local = fmaxf(local, __shfl_xor(local, off));
    if (lane == 0) red8[wid] = local;
    __syncthreads();

    float mres;
    {
        float4 r0 = *(const float4*)&red8[0];
        float4 r1 = *(const float4*)&red8[4];
        float m0 = fmaxf(fmaxf(r0.x, r0.y), fmaxf(r0.z, r0.w));
        float m1 = fmaxf(fmaxf(r1.x, r1.y), fmaxf(r1.z, r1.w));
        mres = fmaxf(m0, m1);
    }
    float invm = 1.f / (mres + EPS);

    // P5: out[b,r,c] = bias[r,c] + res[c,r]*invm * imax[r]*wmax[c]
    const float* wmaxg = ws + WS_WMAX;
    for (int o = t; o < 2450; o += 512) {
        int r = o / 50, c = o - r * 50;
        float val = bias[o];
        if (c >= 12 && c < 38)
            val = fmaf(res_s[c - 12][r] * invm, imax_s[r] * wmaxg[c], val);
        out[b * 2450 + o] = val;
    }
}

extern "C" void kernel_launch(void* const* d_in, const int* in_sizes, int n_in,
                              void* d_out, int out_size, void* d_ws, size_t ws_size,
                              hipStream_t stream) {
    const float* in   = (const float*)d_in[0];   // [512,1,28,28]
    const float* w    = (const float*)d_in[1];   // [50,16]
    const float* bias = (const float*)d_in[2];   // [1,49,50]
    const float* fs   = (const float*)d_in[3];   // [200,200]
    float* out = (float*)d_out;                  // [512,49,50] f32
    float* ws  = (float*)d_ws;

    hipLaunchKernelGGL(k_prelude, dim3(195),  dim3(256), 0, stream, w, fs, ws);
    hipLaunchKernelGGL(k_main,    dim3(512),  dim3(512), 0, stream, in, bias, fs, ws, out);
}

// Round 18
// 23.697 us; speedup vs baseline: 1.1212x; 1.0121x over previous
//
#include <hip/hip_runtime.h>
#include <math.h>

#define EPS 1e-8f

typedef _Float16 h8 __attribute__((ext_vector_type(8)));
typedef float f32x16 __attribute__((ext_vector_type(16)));

// sin/cos of -2*pi*ph/200 via v_sin_f32/v_cos_f32 (input in revolutions, |x|<1)
static __device__ __forceinline__ void fsincos(int ph, float* s, float* c) {
    float x = (float)ph * (-1.0f / 200.0f);
    *s = __builtin_amdgcn_sinf(x);
    *c = __builtin_amdgcn_cosf(x);
}

// ws layout (float offsets)
#define WS_WMAX 0        // 50
#define WS_WN   64       // 800
#define WS_RCPA 1024     // 5200: reciprocal of |fft_sig| window
#define WS_A2   8192     // f16 frags [4 tm][4 pks][64 l][8 s] = 8192 f16 (hi only)
#define WS_B3   16384    // f16 frags [4 tn][16 pks][64 l][8 s] = 32768 f16 (hi+lo, interleaved cols)

// Shared A/B fragment k-map (identical for builders & consumers):
//   row/col = 32*tile + (l&31);  k = 16*ks + 8*(l>>5) + s

// ---- prologue: amp (blocks 0..162) + tables/fragments (163..194) -----------
__global__ __launch_bounds__(256) void k_prelude(const float* __restrict__ w,
                                                 const float* __restrict__ fs,
                                                 float* __restrict__ ws) {
    const int blk = blockIdx.x, t = threadIdx.x;
    if (blk < 163) {
        __shared__ float tc[200], tsn[200];
        for (int i = t; i < 200; i += 256) {
            float s, c;
            fsincos(i, &s, &c);
            tc[i] = c; tsn[i] = s;
        }
        __syncthreads();
        int gid = blk * 256 + t;
        int q = gid >> 3, part = gid & 7;
        float aR = 0.f, aI = 0.f;
        if (q < 5200) {
            int s_ = q / 52, u = q - s_ * 52;
            int k = (150 + s_) % 200;
            int j = 101 + u;
            int ph = (k * (part * 25)) % 200;
            for (int r = part * 25; r < part * 25 + 25; ++r) {
                float v = fs[r * 200 + j];
                aR = fmaf(v, tc[ph], aR);
                aI = fmaf(v, tsn[ph], aI);
                ph += k; if (ph >= 200) ph -= 200;
            }
        }
        aR += __shfl_xor(aR, 1); aI += __shfl_xor(aI, 1);
        aR += __shfl_xor(aR, 2); aI += __shfl_xor(aI, 2);
        aR += __shfl_xor(aR, 4); aI += __shfl_xor(aI, 4);
        if (q < 5200 && part == 0)
            ws[WS_RCPA + q] = 1.0f / sqrtf(aR * aR + aI * aI);
    } else {
        int gid = (blk - 163) * 256 + t;   // 0..8191
        if (gid < 50) {
            float mx = 0.f, vals[16];
            for (int q = 0; q < 16; ++q) {
                float v = fabsf(w[gid * 16 + q]);
                vals[q] = v; mx = fmaxf(mx, v);
            }
            ws[WS_WMAX + gid] = mx;
            float d = mx + EPS;
            for (int q = 0; q < 16; ++q) ws[WS_WN + gid * 16 + q] = vals[q] / d;
        }
        // A2 (hi only) = [cR(50); cI(50); 0] rows x k(0..48)
        {
            _Float16* A2h = (_Float16*)(ws + WS_A2);
            int a = gid;   // exactly 8192 threads
            int s = a & 7, l = (a >> 3) & 63, pks = (a >> 9) & 3, tm = a >> 11;
            int row = 32 * tm + (l & 31);
            int k = 16 * pks + 8 * (l >> 5) + s;
            float X = 0.f;
            if (row < 100 && k < 49) {
                int m = (row < 50) ? row : row - 50;
                int kk = (175 + m) % 200;
                int ph = (kk * (75 + k)) % 200;
                float sn, cs;
                fsincos(ph, &sn, &cs);
                X = (row < 50) ? cs : sn;
            }
            A2h[a] = (_Float16)X;
        }
        // B3 INTERLEAVED: col n' = 2*cc + isI (0..103)
        //   isI=0: kap<64 ? eR : -eI ;  isI=1: kap<64 ? eI : eR
        _Float16* B3h = (_Float16*)(ws + WS_B3);
        for (int bI = gid; bI < 32768; bI += 8192) {
            int s = bI & 7, l = (bI >> 3) & 63, pks = (bI >> 9) & 15, tn = bI >> 13;
            int part = pks >> 3;
            int np = 32 * tn + (l & 31);
            int kap = 16 * (pks & 7) + 8 * (l >> 5) + s;
            float X = 0.f;
            if (np < 104) {
                int cc = np >> 1;
                int j = kap & 63;
                int ph = ((cc + 1) * j) % 200;
                float sn, cs;
                fsincos(ph, &sn, &cs);
                X = (np & 1) ? ((kap < 64) ? sn : cs) : ((kap < 64) ? cs : -sn);
            }
            _Float16 hi = (_Float16)X;
            B3h[bI] = part ? (_Float16)(X - (float)hi) : hi;
        }
    }
}

// -------- main batched kernel: one block (512 thr = 8 waves) per batch ------
__global__ __launch_bounds__(512, 4) void k_main(const float* __restrict__ in,
                                                 const float* __restrict__ bias,
                                                 const float* __restrict__ fs,
                                                 const float* __restrict__ ws,
                                                 float* __restrict__ out) {
    __shared__ __align__(16) char R1[16384];   // B2 hi frags (8KB); later absG f32[2600]
    __shared__ __align__(16) char R2[16640];   // A3 hi frags [2 tm3][8 pks][65 slots][8 s] f16
    __shared__ float xpat[50][16];
    __shared__ float imax_s[50];
    __shared__ float inv_s[50];
    __shared__ float res_s[26][50];
    __shared__ __align__(16) float red8[8];

    const int t = threadIdx.x;
    const int b = blockIdx.x;
    const int lane = t & 63;
    const int wid = t >> 6;                               // 0..7
    const int swid = __builtin_amdgcn_readfirstlane(wid);
    const float* ib = in + b * 784;

    // TOP prefetch 1: fs values for this thread's B2 fragment (indep of P0)
    const int p1_l = t & 63;
    const int p1_ksq = (t >> 6) & 3;
    const int p1_tn = t >> 8;                 // 0..1
    const int p1_j = (p1_l & 31) + 32 * p1_tn;
    const int p1_i0 = 16 * p1_ksq + 8 * (p1_l >> 5);
    float fsv[8];
    #pragma unroll
    for (int s = 0; s < 8; ++s) {
        int i = p1_i0 + s;
        fsv[s] = (i < 49) ? fs[(75 + i) * 200 + p1_j] : 0.f;
    }
    // TOP prefetch 2: A2 fragments for P2 (16 regs; drain under P0/P1 barriers)
    const int tmP = swid >> 1, tnP = swid & 1;
    h8 a2f[4];
    {
        const h8* wsA2 = (const h8*)(ws + WS_A2);
        #pragma unroll
        for (int kq = 0; kq < 4; ++kq) a2f[kq] = wsA2[(tmP * 4 + kq) * 64 + lane];
    }

    // P0: patches (float4) + per-row max via quad shuffle
    if (t < 196) {
        int row = t >> 2, s4 = t & 3;
        int pr = row / 7, pc = row - pr * 7;
        float4 v4 = *(const float4*)(ib + (pr * 4 + s4) * 28 + pc * 4);
        *(float4*)(&xpat[row][s4 * 4]) = v4;
        float mx = fmaxf(fmaxf(v4.x, v4.y), fmaxf(v4.z, v4.w));
        mx = fmaxf(mx, __shfl_xor(mx, 1));
        mx = fmaxf(mx, __shfl_xor(mx, 2));
        if (s4 == 0) { imax_s[row] = mx; inv_s[row] = 1.f / (mx + EPS); }
    }
    __syncthreads();

    // P1: B2 hi frags from prefetched fs; one ds_write_b128 per thread
    {
        h8 hiv;
        #pragma unroll
        for (int s = 0; s < 8; ++s) {
            int i = p1_i0 + s;
            float v = 0.f;
            if (i < 49) v = fsv[s] * xpat[i][p1_j >> 2] * inv_s[i];
            hiv[s] = (_Float16)v;
        }
        _Float16* B2h = (_Float16*)R1;
        *(h8*)(B2h + ((p1_tn * 4 + p1_ksq) * 64 + p1_l) * 8) = hiv;
    }
    __syncthreads();

    // P2: ph2 MFMA D[128][64] = c_hi @ T_hi, 4 K-steps (A2 already in regs);
    // epilogue scatters D*wn (hi f16) into padded A3 frag layout
    {
        f32x16 acc;
        #pragma unroll
        for (int i = 0; i < 16; ++i) acc[i] = 0.f;
        #pragma unroll
        for (int kq = 0; kq < 4; ++kq) {
            h8 bhi = *(const h8*)(R1 + (((tnP * 4 + kq) * 64 + lane) << 4));
            acc = __builtin_amdgcn_mfma_f32_32x32x16_f16(a2f[kq], bhi, acc, 0, 0, 0);
        }
        const float* wn = ws + WS_WN;
        const int j = (lane & 31) + 32 * tnP;
        const int q = j >> 2;
        _Float16* A3h = (_Float16*)R2;
        #pragma unroll
        for (int r = 0; r < 16; ++r) {
            int row = (r & 3) + 8 * (r >> 2) + 4 * (lane >> 5) + 32 * tmP;
            if (row < 100) {
                int m = (row < 50) ? row : row - 50;
                float v = acc[r] * wn[m * 16 + q];
                int kap = j + ((row < 50) ? 0 : 64);
                int tmw = m >> 5;
                int pks = kap >> 4;                    // 0..7
                int bb = (kap >> 3) & 1;
                int elem = ((tmw * 8 + pks) * 65 + (m & 31) + 33 * bb) * 8 + (kap & 7);
                A3h[elem] = (_Float16)v;
            }
        }
    }
    __syncthreads();

    // P4 o-indices for RCPA prefetch (issued inside P3, consumed in P4)
    const int o0 = t, o1 = t + 512, o2 = t + 1024;   // o0,o1 always < 1300; o2 iff t<276
    float raA[6], raB[6], raC[6];

    // P3: ph3 MFMA G'[64][128] = O_hi @ (B_hi + B_lo), 16 K-steps, dual acc;
    // RCPA prefetch after the chain; epilogue fuses |G| -> absG (overlays R1)
    {
        const int tm3 = swid >> 2, tn3 = swid & 3;
        f32x16 acc0, acc1;
        #pragma unroll
        for (int i = 0; i < 16; ++i) { acc0[i] = 0.f; acc1[i] = 0.f; }
        const h8* wsB3 = (const h8*)(ws + WS_B3);
        const int aoff = lane + (lane >> 5);           // padded read index
        #pragma unroll
        for (int kq = 0; kq < 8; ++kq) {
            h8 a   = *(const h8*)(R2 + (((tm3 * 8 + kq) * 65 + aoff) << 4));
            h8 bhi = wsB3[(tn3 * 16 + kq) * 64 + lane];
            h8 blo = wsB3[(tn3 * 16 + kq + 8) * 64 + lane];
            acc0 = __builtin_amdgcn_mfma_f32_32x32x16_f16(a, bhi, acc0, 0, 0, 0);
            acc1 = __builtin_amdgcn_mfma_f32_32x32x16_f16(a, blo, acc1, 0, 0, 0);
        }
        // RCPA prefetch: drains under epilogue + end barrier
        {
            const float* ra = ws + WS_RCPA;
            {
                int hh = o0 / 50, w2 = o0 - hh * 50, h = hh + 12;
                const float* r0p = ra + (2 * h) * 52 + w2;
                raA[0] = r0p[0]; raA[1] = r0p[1]; raA[2] = r0p[2];
                raA[3] = r0p[52]; raA[4] = r0p[53]; raA[5] = r0p[54];
            }
            {
                int hh = o1 / 50, w2 = o1 - hh * 50, h = hh + 12;
                const float* r0p = ra + (2 * h) * 52 + w2;
                raB[0] = r0p[0]; raB[1] = r0p[1]; raB[2] = r0p[2];
                raB[3] = r0p[52]; raB[4] = r0p[53]; raB[5] = r0p[54];
            }
            if (o2 < 1300) {
                int hh = o2 / 50, w2 = o2 - hh * 50, h = hh + 12;
                const float* r0p = ra + (2 * h) * 52 + w2;
                raC[0] = r0p[0]; raC[1] = r0p[1]; raC[2] = r0p[2];
                raC[3] = r0p[52]; raC[4] = r0p[53]; raC[5] = r0p[54];
            }
        }
        f32x16 acc = acc0 + acc1;
        const int np = (lane & 31) + 32 * tn3;
        float* aG = (float*)R1;
        if (np < 104) {
            const int cc = np >> 1;
            const bool wr = !(np & 1);
            #pragma unroll
            for (int r = 0; r < 16; ++r) {
                int row = (r & 3) + 8 * (r >> 2) + 4 * (lane >> 5) + 32 * tm3;
                float g = acc[r];
                float gp = __shfl_xor(g, 1);
                if (row < 50 && wr) aG[row * 52 + cc] = sqrtf(g * g + gp * gp);
            }
        }
    }
    __syncthreads();

    // P4: pool absG (2x3/2x1); r = v * min(prefetched rcp-amp window)
    const float* aG = (const float*)R1;
    float local = 0.f;
    {
        int hh = o0 / 50, w2 = o0 - hh * 50, h = hh + 12;
        int m1 = 2 * h - 25, m2 = m1 + 1;
        float v = 0.f;
        #pragma unroll
        for (int du = 0; du < 3; ++du) {
            int u = w2 + du;
            if (m1 >= 0) v = fmaxf(v, aG[m1 * 52 + u]);
            if (m2 < 50) v = fmaxf(v, aG[m2 * 52 + u]);
        }
        float rc = fminf(fminf(fminf(raA[0], raA[1]), fminf(raA[2], raA[3])),
                         fminf(raA[4], raA[5]));
        float r = v * rc;
        res_s[hh][w2] = r;
        local = fmaxf(local, r);
    }
    {
        int hh = o1 / 50, w2 = o1 - hh * 50, h = hh + 12;
        int m1 = 2 * h - 25, m2 = m1 + 1;
        float v = 0.f;
        #pragma unroll
        for (int du = 0; du < 3; ++du) {
            int u = w2 + du;
            if (m1 >= 0) v = fmaxf(v, aG[m1 * 52 + u]);
            if (m2 < 50) v = fmaxf(v, aG[m2 * 52 + u]);
        }
        float rc = fminf(fminf(fminf(raB[0], raB[1]), fminf(raB[2], raB[3])),
                         fminf(raB[4], raB[5]));
        float r = v * rc;
        res_s[hh][w2] = r;
        local = fmaxf(local, r);
    }
    if (o2 < 1300) {
        int hh = o2 / 50, w2 = o2 - hh * 50, h = hh + 12;
        int m1 = 2 * h - 25, m2 = m1 + 1;
        float v = 0.f;
        #pragma unroll
        for (int du = 0; du < 3; ++du) {
            int u = w2 + du;
            if (m1 >= 0) v = fmaxf(v, aG[m1 * 52 + u]);
            if (m2 < 50) v = fmaxf(v, aG[m2 * 52 + u]);
        }
        float rc = fminf(fminf(fminf(raC[0], raC[1]), fminf(raC[2], raC[3])),
                         fminf(raC[4], raC[5]));
        float r = v * rc;
        res_s[hh][w2] = r;
        local = fmaxf(local, r);
    }
    #pragma unroll
    for (int off = 32; off > 0; off >>= 1)
        local = fmaxf(local, __shfl_xor(local, off));
    if (lane == 0) red8[wid] = local;

    // bias prefetch for P5 (drains under the P4 barrier)
    float bv[5];
    #pragma unroll
    for (int k2 = 0; k2 < 5; ++k2) {
        int o = t + k2 * 512;
        bv[k2] = (o < 2450) ? bias[o] : 0.f;
    }
    __syncthreads();

    float mres;
    {
        float4 r0 = *(const float4*)&red8[0];
        float4 r1 = *(const float4*)&red8[4];
        float m0 = fmaxf(fmaxf(r0.x, r0.y), fmaxf(r0.z, r0.w));
        float m1 = fmaxf(fmaxf(r1.x, r1.y), fmaxf(r1.z, r1.w));
        mres = fmaxf(m0, m1);
    }
    float invm = 1.f / (mres + EPS);

    // P5: out[b,r,c] = bias[r,c] + res[c,r]*invm * imax[r]*wmax[c]
    const float* wmaxg = ws + WS_WMAX;
    #pragma unroll
    for (int k2 = 0; k2 < 5; ++k2) {
        int o = t + k2 * 512;
        if (o < 2450) {
            int r = o / 50, c = o - r * 50;
            float val = bv[k2];
            if (c >= 12 && c < 38)
                val = fmaf(res_s[c - 12][r] * invm, imax_s[r] * wmaxg[c], val);
            out[b * 2450 + o] = val;
        }
    }
}

extern "C" void kernel_launch(void* const* d_in, const int* in_sizes, int n_in,
                              void* d_out, int out_size, void* d_ws, size_t ws_size,
                              hipStream_t stream) {
    const float* in   = (const float*)d_in[0];   // [512,1,28,28]
    const float* w    = (const float*)d_in[1];   // [50,16]
    const float* bias = (const float*)d_in[2];   // [1,49,50]
    const float* fs   = (const float*)d_in[3];   // [200,200]
    float* out = (float*)d_out;                  // [512,49,50] f32
    float* ws  = (float*)d_ws;

    hipLaunchKernelGGL(k_prelude, dim3(195),  dim3(256), 0, stream, w, fs, ws);
    hipLaunchKernelGGL(k_main,    dim3(512),  dim3(512), 0, stream, in, bias, fs, ws, out);
}

// Round 19
// 23.636 us; speedup vs baseline: 1.1241x; 1.0026x over previous
//
#include <hip/hip_runtime.h>
#include <math.h>

#define EPS 1e-8f

typedef _Float16 h8 __attribute__((ext_vector_type(8)));
typedef float f32x16 __attribute__((ext_vector_type(16)));

// sin/cos of -2*pi*ph/200 via v_sin_f32/v_cos_f32 (input in revolutions, |x|<1)
static __device__ __forceinline__ void fsincos(int ph, float* s, float* c) {
    float x = (float)ph * (-1.0f / 200.0f);
    *s = __builtin_amdgcn_sinf(x);
    *c = __builtin_amdgcn_cosf(x);
}

// ws layout (float offsets)
#define WS_WMAX 0        // 50
#define WS_WN   64       // 800
#define WS_RCPA 1024     // 5200 layout; only rows 24..75 (q in [1248,3952)) computed/consumed
#define WS_A2   8192     // f16 frags [4 tm][4 pks][64 l][8 s] = 8192 f16 (hi only)
#define WS_B3   16384    // f16 frags [4 tn][16 pks][64 l][8 s] = 32768 f16 (hi+lo, interleaved cols)

// Shared A/B fragment k-map (identical for builders & consumers):
//   row/col = 32*tile + (l&31);  k = 16*ks + 8*(l>>5) + s

// ---- prologue: amp rows 24..75, 16-way split (blocks 0..168) + tables (169..200)
__global__ __launch_bounds__(256) void k_prelude(const float* __restrict__ w,
                                                 const float* __restrict__ fs,
                                                 float* __restrict__ ws) {
    const int blk = blockIdx.x, t = threadIdx.x;
    if (blk < 169) {
        // 1/|fft(full_sig,axis=0)| at shifted rows 24..75 of the 100-row window,
        // cols 101..152. 169*256 threads = 2704 values x 16 parts exactly.
        int gid = blk * 256 + t;
        int v = gid >> 4, part = gid & 15;
        int q = 1248 + v;                 // q in [1248, 3952)
        int s_ = q / 52, u = q - s_ * 52;
        int k = (150 + s_) % 200;
        int j = 101 + u;
        int r0 = part * 13;
        int r1 = (r0 + 13 < 200) ? r0 + 13 : 200;
        // rotation-recurrence twiddles: w_r = exp(-2pi*i*(k*r)/200)
        float cs, sn, stc, sts;
        fsincos((k * r0) % 200, &sn, &cs);
        fsincos(k, &sts, &stc);
        float aR = 0.f, aI = 0.f;
        for (int r = r0; r < r1; ++r) {
            float vv = fs[r * 200 + j];
            aR = fmaf(vv, cs, aR);
            aI = fmaf(vv, sn, aI);
            float nc = cs * stc - sn * sts;
            float ns = sn * stc + cs * sts;
            cs = nc; sn = ns;
        }
        aR += __shfl_xor(aR, 1); aI += __shfl_xor(aI, 1);
        aR += __shfl_xor(aR, 2); aI += __shfl_xor(aI, 2);
        aR += __shfl_xor(aR, 4); aI += __shfl_xor(aI, 4);
        aR += __shfl_xor(aR, 8); aI += __shfl_xor(aI, 8);
        if (part == 0)
            ws[WS_RCPA + q] = 1.0f / sqrtf(aR * aR + aI * aI);
    } else {
        int gid = (blk - 169) * 256 + t;   // 0..8191
        if (gid < 50) {
            float mx = 0.f, vals[16];
            for (int q = 0; q < 16; ++q) {
                float v = fabsf(w[gid * 16 + q]);
                vals[q] = v; mx = fmaxf(mx, v);
            }
            ws[WS_WMAX + gid] = mx;
            float d = mx + EPS;
            for (int q = 0; q < 16; ++q) ws[WS_WN + gid * 16 + q] = vals[q] / d;
        }
        // A2 (hi only) = [cR(50); cI(50); 0] rows x k(0..48)
        {
            _Float16* A2h = (_Float16*)(ws + WS_A2);
            int a = gid;   // exactly 8192 threads
            int s = a & 7, l = (a >> 3) & 63, pks = (a >> 9) & 3, tm = a >> 11;
            int row = 32 * tm + (l & 31);
            int k = 16 * pks + 8 * (l >> 5) + s;
            float X = 0.f;
            if (row < 100 && k < 49) {
                int m = (row < 50) ? row : row - 50;
                int kk = (175 + m) % 200;
                int ph = (kk * (75 + k)) % 200;
                float sn, cs;
                fsincos(ph, &sn, &cs);
                X = (row < 50) ? cs : sn;
            }
            A2h[a] = (_Float16)X;
        }
        // B3 INTERLEAVED: col n' = 2*cc + isI (0..103)
        //   isI=0: kap<64 ? eR : -eI ;  isI=1: kap<64 ? eI : eR
        _Float16* B3h = (_Float16*)(ws + WS_B3);
        for (int bI = gid; bI < 32768; bI += 8192) {
            int s = bI & 7, l = (bI >> 3) & 63, pks = (bI >> 9) & 15, tn = bI >> 13;
            int part = pks >> 3;
            int np = 32 * tn + (l & 31);
            int kap = 16 * (pks & 7) + 8 * (l >> 5) + s;
            float X = 0.f;
            if (np < 104) {
                int cc = np >> 1;
                int j = kap & 63;
                int ph = ((cc + 1) * j) % 200;
                float sn, cs;
                fsincos(ph, &sn, &cs);
                X = (np & 1) ? ((kap < 64) ? sn : cs) : ((kap < 64) ? cs : -sn);
            }
            _Float16 hi = (_Float16)X;
            B3h[bI] = part ? (_Float16)(X - (float)hi) : hi;
        }
    }
}

// -------- main batched kernel: one block (512 thr = 8 waves) per batch ------
__global__ __launch_bounds__(512, 4) void k_main(const float* __restrict__ in,
                                                 const float* __restrict__ bias,
                                                 const float* __restrict__ fs,
                                                 const float* __restrict__ ws,
                                                 float* __restrict__ out) {
    __shared__ __align__(16) char R1[16384];   // B2 hi frags (8KB); later absG f32[2600]
    __shared__ __align__(16) char R2[16640];   // A3 hi frags [2 tm3][8 pks][65 slots][8 s] f16
    __shared__ float xpat[50][16];
    __shared__ float imax_s[50];
    __shared__ float inv_s[50];
    __shared__ float res_s[26][50];
    __shared__ __align__(16) float red8[8];

    const int t = threadIdx.x;
    const int b = blockIdx.x;
    const int lane = t & 63;
    const int wid = t >> 6;                               // 0..7
    const int swid = __builtin_amdgcn_readfirstlane(wid);
    const float* ib = in + b * 784;

    // TOP prefetch 1: fs values for this thread's B2 fragment (indep of P0)
    const int p1_l = t & 63;
    const int p1_ksq = (t >> 6) & 3;
    const int p1_tn = t >> 8;                 // 0..1
    const int p1_j = (p1_l & 31) + 32 * p1_tn;
    const int p1_i0 = 16 * p1_ksq + 8 * (p1_l >> 5);
    float fsv[8];
    #pragma unroll
    for (int s = 0; s < 8; ++s) {
        int i = p1_i0 + s;
        fsv[s] = (i < 49) ? fs[(75 + i) * 200 + p1_j] : 0.f;
    }
    // TOP prefetch 2: A2 fragments for P2 (16 regs; drain under P0/P1 barriers)
    const int tmP = swid >> 1, tnP = swid & 1;
    h8 a2f[4];
    {
        const h8* wsA2 = (const h8*)(ws + WS_A2);
        #pragma unroll
        for (int kq = 0; kq < 4; ++kq) a2f[kq] = wsA2[(tmP * 4 + kq) * 64 + lane];
    }

    // P0: patches (float4) + per-row max via quad shuffle
    if (t < 196) {
        int row = t >> 2, s4 = t & 3;
        int pr = row / 7, pc = row - pr * 7;
        float4 v4 = *(const float4*)(ib + (pr * 4 + s4) * 28 + pc * 4);
        *(float4*)(&xpat[row][s4 * 4]) = v4;
        float mx = fmaxf(fmaxf(v4.x, v4.y), fmaxf(v4.z, v4.w));
        mx = fmaxf(mx, __shfl_xor(mx, 1));
        mx = fmaxf(mx, __shfl_xor(mx, 2));
        if (s4 == 0) { imax_s[row] = mx; inv_s[row] = 1.f / (mx + EPS); }
    }
    __syncthreads();

    // P1: B2 hi frags from prefetched fs; one ds_write_b128 per thread
    {
        h8 hiv;
        #pragma unroll
        for (int s = 0; s < 8; ++s) {
            int i = p1_i0 + s;
            float v = 0.f;
            if (i < 49) v = fsv[s] * xpat[i][p1_j >> 2] * inv_s[i];
            hiv[s] = (_Float16)v;
        }
        _Float16* B2h = (_Float16*)R1;
        *(h8*)(B2h + ((p1_tn * 4 + p1_ksq) * 64 + p1_l) * 8) = hiv;
    }
    __syncthreads();

    // P2: ph2 MFMA D[128][64] = c_hi @ T_hi, 4 K-steps (A2 already in regs);
    // epilogue scatters D*wn (hi f16) into padded A3 frag layout
    {
        f32x16 acc;
        #pragma unroll
        for (int i = 0; i < 16; ++i) acc[i] = 0.f;
        #pragma unroll
        for (int kq = 0; kq < 4; ++kq) {
            h8 bhi = *(const h8*)(R1 + (((tnP * 4 + kq) * 64 + lane) << 4));
            acc = __builtin_amdgcn_mfma_f32_32x32x16_f16(a2f[kq], bhi, acc, 0, 0, 0);
        }
        const float* wn = ws + WS_WN;
        const int j = (lane & 31) + 32 * tnP;
        const int q = j >> 2;
        _Float16* A3h = (_Float16*)R2;
        #pragma unroll
        for (int r = 0; r < 16; ++r) {
            int row = (r & 3) + 8 * (r >> 2) + 4 * (lane >> 5) + 32 * tmP;
            if (row < 100) {
                int m = (row < 50) ? row : row - 50;
                float v = acc[r] * wn[m * 16 + q];
                int kap = j + ((row < 50) ? 0 : 64);
                int tmw = m >> 5;
                int pks = kap >> 4;                    // 0..7
                int bb = (kap >> 3) & 1;
                int elem = ((tmw * 8 + pks) * 65 + (m & 31) + 33 * bb) * 8 + (kap & 7);
                A3h[elem] = (_Float16)v;
            }
        }
    }
    __syncthreads();

    // P4 o-indices for RCPA prefetch (issued inside P3, consumed in P4)
    const int o0 = t, o1 = t + 512, o2 = t + 1024;   // o0,o1 always < 1300; o2 iff t<276
    float raA[6], raB[6], raC[6];

    // P3: ph3 MFMA G'[64][128] = O_hi @ (B_hi + B_lo), 16 K-steps, dual acc;
    // RCPA prefetch after the chain; epilogue fuses |G| -> absG (overlays R1)
    {
        const int tm3 = swid >> 2, tn3 = swid & 3;
        f32x16 acc0, acc1;
        #pragma unroll
        for (int i = 0; i < 16; ++i) { acc0[i] = 0.f; acc1[i] = 0.f; }
        const h8* wsB3 = (const h8*)(ws + WS_B3);
        const int aoff = lane + (lane >> 5);           // padded read index
        #pragma unroll
        for (int kq = 0; kq < 8; ++kq) {
            h8 a   = *(const h8*)(R2 + (((tm3 * 8 + kq) * 65 + aoff) << 4));
            h8 bhi = wsB3[(tn3 * 16 + kq) * 64 + lane];
            h8 blo = wsB3[(tn3 * 16 + kq + 8) * 64 + lane];
            acc0 = __builtin_amdgcn_mfma_f32_32x32x16_f16(a, bhi, acc0, 0, 0, 0);
            acc1 = __builtin_amdgcn_mfma_f32_32x32x16_f16(a, blo, acc1, 0, 0, 0);
        }
        // RCPA prefetch: drains under epilogue + end barrier
        {
            const float* ra = ws + WS_RCPA;
            {
                int hh = o0 / 50, w2 = o0 - hh * 50, h = hh + 12;
                const float* r0p = ra + (2 * h) * 52 + w2;
                raA[0] = r0p[0]; raA[1] = r0p[1]; raA[2] = r0p[2];
                raA[3] = r0p[52]; raA[4] = r0p[53]; raA[5] = r0p[54];
            }
            {
                int hh = o1 / 50, w2 = o1 - hh * 50, h = hh + 12;
                const float* r0p = ra + (2 * h) * 52 + w2;
                raB[0] = r0p[0]; raB[1] = r0p[1]; raB[2] = r0p[2];
                raB[3] = r0p[52]; raB[4] = r0p[53]; raB[5] = r0p[54];
            }
            if (o2 < 1300) {
                int hh = o2 / 50, w2 = o2 - hh * 50, h = hh + 12;
                const float* r0p = ra + (2 * h) * 52 + w2;
                raC[0] = r0p[0]; raC[1] = r0p[1]; raC[2] = r0p[2];
                raC[3] = r0p[52]; raC[4] = r0p[53]; raC[5] = r0p[54];
            }
        }
        f32x16 acc = acc0 + acc1;
        const int np = (lane & 31) + 32 * tn3;
        float* aG = (float*)R1;
        if (np < 104) {
            const int cc = np >> 1;
            const bool wr = !(np & 1);
            #pragma unroll
            for (int r = 0; r < 16; ++r) {
                int row = (r & 3) + 8 * (r >> 2) + 4 * (lane >> 5) + 32 * tm3;
                float g = acc[r];
                float gp = __shfl_xor(g, 1);
                if (row < 50 && wr) aG[row * 52 + cc] = sqrtf(g * g + gp * gp);
            }
        }
    }
    __syncthreads();

    // P4: pool absG (2x3/2x1); r = v * min(prefetched rcp-amp window)
    const float* aG = (const float*)R1;
    float local = 0.f;
    {
        int hh = o0 / 50, w2 = o0 - hh * 50, h = hh + 12;
        int m1 = 2 * h - 25, m2 = m1 + 1;
        float v = 0.f;
        #pragma unroll
        for (int du = 0; du < 3; ++du) {
            int u = w2 + du;
            if (m1 >= 0) v = fmaxf(v, aG[m1 * 52 + u]);
            if (m2 < 50) v = fmaxf(v, aG[m2 * 52 + u]);
        }
        float rc = fminf(fminf(fminf(raA[0], raA[1]), fminf(raA[2], raA[3])),
                         fminf(raA[4], raA[5]));
        float r = v * rc;
        res_s[hh][w2] = r;
        local = fmaxf(local, r);
    }
    {
        int hh = o1 / 50, w2 = o1 - hh * 50, h = hh + 12;
        int m1 = 2 * h - 25, m2 = m1 + 1;
        float v = 0.f;
        #pragma unroll
        for (int du = 0; du < 3; ++du) {
            int u = w2 + du;
            if (m1 >= 0) v = fmaxf(v, aG[m1 * 52 + u]);
            if (m2 < 50) v = fmaxf(v, aG[m2 * 52 + u]);
        }
        float rc = fminf(fminf(fminf(raB[0], raB[1]), fminf(raB[2], raB[3])),
                         fminf(raB[4], raB[5]));
        float r = v * rc;
        res_s[hh][w2] = r;
        local = fmaxf(local, r);
    }
    if (o2 < 1300) {
        int hh = o2 / 50, w2 = o2 - hh * 50, h = hh + 12;
        int m1 = 2 * h - 25, m2 = m1 + 1;
        float v = 0.f;
        #pragma unroll
        for (int du = 0; du < 3; ++du) {
            int u = w2 + du;
            if (m1 >= 0) v = fmaxf(v, aG[m1 * 52 + u]);
            if (m2 < 50) v = fmaxf(v, aG[m2 * 52 + u]);
        }
        float rc = fminf(fminf(fminf(raC[0], raC[1]), fminf(raC[2], raC[3])),
                         fminf(raC[4], raC[5]));
        float r = v * rc;
        res_s[hh][w2] = r;
        local = fmaxf(local, r);
    }
    #pragma unroll
    for (int off = 32; off > 0; off >>= 1)
        local = fmaxf(local, __shfl_xor(local, off));
    if (lane == 0) red8[wid] = local;

    // bias prefetch for P5 (drains under the P4 barrier)
    float bv[5];
    #pragma unroll
    for (int k2 = 0; k2 < 5; ++k2) {
        int o = t + k2 * 512;
        bv[k2] = (o < 2450) ? bias[o] : 0.f;
    }
    __syncthreads();

    float mres;
    {
        float4 r0 = *(const float4*)&red8[0];
        float4 r1 = *(const float4*)&red8[4];
        float m0 = fmaxf(fmaxf(r0.x, r0.y), fmaxf(r0.z, r0.w));
        float m1 = fmaxf(fmaxf(r1.x, r1.y), fmaxf(r1.z, r1.w));
        mres = fmaxf(m0, m1);
    }
    float invm = 1.f / (mres + EPS);

    // P5: out[b,r,c] = bias[r,c] + res[c,r]*invm * imax[r]*wmax[c]
    const float* wmaxg = ws + WS_WMAX;
    #pragma unroll
    for (int k2 = 0; k2 < 5; ++k2) {
        int o = t + k2 * 512;
        if (o < 2450) {
            int r = o / 50, c = o - r * 50;
            float val = bv[k2];
            if (c >= 12 && c < 38)
                val = fmaf(res_s[c - 12][r] * invm, imax_s[r] * wmaxg[c], val);
            out[b * 2450 + o] = val;
        }
    }
}

extern "C" void kernel_launch(void* const* d_in, const int* in_sizes, int n_in,
                              void* d_out, int out_size, void* d_ws, size_t ws_size,
                              hipStream_t stream) {
    const float* in   = (const float*)d_in[0];   // [512,1,28,28]
    const float* w    = (const float*)d_in[1];   // [50,16]
    const float* bias = (const float*)d_in[2];   // [1,49,50]
    const float* fs   = (const float*)d_in[3];   // [200,200]
    float* out = (float*)d_out;                  // [512,49,50] f32
    float* ws  = (float*)d_ws;

    hipLaunchKernelGGL(k_prelude, dim3(201),  dim3(256), 0, stream, w, fs, ws);
    hipLaunchKernelGGL(k_main,    dim3(512),  dim3(512), 0, stream, in, bias, fs, ws, out);
}